// Round 4
// baseline (176.818 us; speedup 1.0000x reference)
//
#include <hip/hip_runtime.h>
#include <hip/hip_fp16.h>

#define K_DIM 1024

typedef _Float16 f16x8 __attribute__((ext_vector_type(8)));
typedef _Float16 f16x4 __attribute__((ext_vector_type(4)));
typedef float f32x4_t __attribute__((ext_vector_type(4)));

// ---------------- f32 -> f16 conversion ----------------
__global__ __launch_bounds__(256) void cvt_f32_to_f16(const float* __restrict__ in,
                                                      _Float16* __restrict__ out, int n4) {
  int stride = gridDim.x * blockDim.x;
  for (int i = blockIdx.x * blockDim.x + threadIdx.x; i < n4; i += stride) {
    float4 v = reinterpret_cast<const float4*>(in)[i];
    f16x4 h;
    h[0] = (_Float16)v.x; h[1] = (_Float16)v.y; h[2] = (_Float16)v.z; h[3] = (_Float16)v.w;
    reinterpret_cast<f16x4*>(out)[i] = h;
  }
}

// ---------------- NT GEMM: C[M,1024] = A[M,1024] @ W[1024,1024]^T + b ----------------
// 128x128 tile, BK=32, 4 waves (2x2), 4x4 16x16x32 fragments per wave.
// blockIdx.z selects (Wa,ba,Ca) vs (Wb,bb,Cb) to fuse twin GEMMs in one launch.
template <bool OUTH>
__global__ __launch_bounds__(256) void gemm_nt(
    const _Float16* __restrict__ A,
    const _Float16* __restrict__ Wa, const _Float16* __restrict__ Wb,
    const float* __restrict__ ba, const float* __restrict__ bb,
    void* __restrict__ Ca, void* __restrict__ Cb) {
  const _Float16* __restrict__ W = (blockIdx.z == 0) ? Wa : Wb;
  const float* __restrict__ bias = (blockIdx.z == 0) ? ba : bb;
  void* __restrict__ Cv = (blockIdx.z == 0) ? Ca : Cb;

  __shared__ _Float16 Ash[128][40];  // 32 + 8 pad (rows stay 16B aligned, banks spread)
  __shared__ _Float16 Bsh[128][40];

  const int tid = threadIdx.x;
  const int lane = tid & 63;
  const int wave = tid >> 6;
  const int wr = wave >> 1;  // 0..1
  const int wc = wave & 1;   // 0..1

  const int tm = blockIdx.x * 128;
  const int tn = blockIdx.y * 128;

  const int r0 = tid >> 2;         // 0..63
  const int kk0 = (tid & 3) * 8;   // 0,8,16,24

  const _Float16* Ag0 = A + (size_t)(tm + r0) * K_DIM + kk0;
  const _Float16* Ag1 = A + (size_t)(tm + r0 + 64) * K_DIM + kk0;
  const _Float16* Bg0 = W + (size_t)(tn + r0) * K_DIM + kk0;
  const _Float16* Bg1 = W + (size_t)(tn + r0 + 64) * K_DIM + kk0;

  f32x4_t acc[4][4];
#pragma unroll
  for (int m = 0; m < 4; ++m)
#pragma unroll
    for (int n = 0; n < 4; ++n) acc[m][n] = (f32x4_t){0.f, 0.f, 0.f, 0.f};

  // prefetch k-tile 0
  uint4 pa0 = *(const uint4*)(Ag0);
  uint4 pa1 = *(const uint4*)(Ag1);
  uint4 pb0 = *(const uint4*)(Bg0);
  uint4 pb1 = *(const uint4*)(Bg1);

  const int fr = lane & 15;
  const int kc = (lane >> 4) * 8;

#pragma unroll 1
  for (int kt = 0; kt < K_DIM / 32; ++kt) {
    __syncthreads();  // previous compute done reading LDS
    *(uint4*)&Ash[r0][kk0] = pa0;
    *(uint4*)&Ash[r0 + 64][kk0] = pa1;
    *(uint4*)&Bsh[r0][kk0] = pb0;
    *(uint4*)&Bsh[r0 + 64][kk0] = pb1;
    __syncthreads();
    if (kt + 1 < K_DIM / 32) {  // prefetch next k-tile, overlaps with MFMA below
      const int koff = (kt + 1) * 32;
      pa0 = *(const uint4*)(Ag0 + koff);
      pa1 = *(const uint4*)(Ag1 + koff);
      pb0 = *(const uint4*)(Bg0 + koff);
      pb1 = *(const uint4*)(Bg1 + koff);
    }
    f16x8 af[4], bf[4];
#pragma unroll
    for (int m = 0; m < 4; ++m) af[m] = *(const f16x8*)&Ash[wr * 64 + m * 16 + fr][kc];
#pragma unroll
    for (int n = 0; n < 4; ++n) bf[n] = *(const f16x8*)&Bsh[wc * 64 + n * 16 + fr][kc];
#pragma unroll
    for (int m = 0; m < 4; ++m)
#pragma unroll
      for (int n = 0; n < 4; ++n)
        acc[m][n] = __builtin_amdgcn_mfma_f32_16x16x32_f16(af[m], bf[n], acc[m][n], 0, 0, 0);
  }

  // epilogue: C/D layout col=lane&15, row=(lane>>4)*4+reg
  const int cr = (lane >> 4) * 4;
  const int cc = lane & 15;
#pragma unroll
  for (int m = 0; m < 4; ++m) {
#pragma unroll
    for (int n = 0; n < 4; ++n) {
      const int col = tn + wc * 64 + n * 16 + cc;
      const float bv = bias[col];
#pragma unroll
      for (int r = 0; r < 4; ++r) {
        const int row = tm + wr * 64 + m * 16 + cr + r;
        float v = acc[m][n][r] + bv;
        if (OUTH)
          ((_Float16*)Cv)[(size_t)row * 1024 + col] = (_Float16)v;
        else
          ((float*)Cv)[(size_t)row * 1024 + col] = v;
      }
    }
  }
}

// ---------------- block-diagonal attention ----------------
// grid (32 groups, 16 heads), 256 threads. Q block 128x64, K/V block 32x64.
// thread pair (p, half): half handles 16 of the 32 text tokens for scores,
// then 32 of the 64 head dims for PV.
__global__ __launch_bounds__(256) void attn_kernel(
    const float* __restrict__ Q, const float* __restrict__ Kf, const float* __restrict__ Vf,
    float* __restrict__ attn_out,  // [16,4096,1024] slice of d_out (pre-zeroed)
    _Float16* __restrict__ ctx) {  // [4096,1024] fp16
  const int g = blockIdx.x;
  const int h = blockIdx.y;

  __shared__ float Ksh[32][68];   // pad 68: rows 16B aligned for float4
  __shared__ float Vsh[32][68];
  __shared__ float Arow[128][33]; // pad 33: conflict-free scalar access

  const int tid = threadIdx.x;

#pragma unroll
  for (int i = 0; i < 8; ++i) {
    int idx = tid + i * 256;  // 0..2047
    int t = idx >> 6, d = idx & 63;
    Ksh[t][d] = Kf[(size_t)(g * 32 + t) * 1024 + h * 64 + d];
    Vsh[t][d] = Vf[(size_t)(g * 32 + t) * 1024 + h * 64 + d];
  }
  __syncthreads();

  const int p = tid >> 1;
  const int half = tid & 1;

  float4 qv[16];
  const float* qrow = Q + (size_t)(g * 128 + p) * 1024 + h * 64;
#pragma unroll
  for (int i = 0; i < 16; ++i) qv[i] = ((const float4*)qrow)[i];

  float s[16];
#pragma unroll
  for (int j = 0; j < 16; ++j) {
    int t = half * 16 + j;
    float acc = 0.f;
#pragma unroll
    for (int d4 = 0; d4 < 16; ++d4) {
      float4 kv = *(const float4*)&Ksh[t][d4 * 4];
      acc += qv[d4].x * kv.x + qv[d4].y * kv.y + qv[d4].z * kv.z + qv[d4].w * kv.w;
    }
    s[j] = acc * 0.125f;  // 1/sqrt(64)
  }

  // softmax over 32 = 16 local + partner lane (tid^1 shares row p)
  float m = s[0];
#pragma unroll
  for (int j = 1; j < 16; ++j) m = fmaxf(m, s[j]);
  m = fmaxf(m, __shfl_xor(m, 1));
  float e[16];
  float sum = 0.f;
#pragma unroll
  for (int j = 0; j < 16; ++j) {
    e[j] = __expf(s[j] - m);
    sum += e[j];
  }
  sum += __shfl_xor(sum, 1);
  const float inv = 1.0f / sum;

  float* arow_out =
      attn_out + (size_t)h * 4096 * 1024 + (size_t)(g * 128 + p) * 1024 + g * 32 + half * 16;
#pragma unroll
  for (int j = 0; j < 16; ++j) {
    float a = e[j] * inv;
    arow_out[j] = a;
    Arow[p][half * 16 + j] = a;
  }
  __syncthreads();

  // PV: ctx[p][half*32 + 0..31]
  float4 acc4[8];
#pragma unroll
  for (int i = 0; i < 8; ++i) acc4[i] = (float4){0.f, 0.f, 0.f, 0.f};
#pragma unroll
  for (int t = 0; t < 32; ++t) {
    float av = Arow[p][t];
#pragma unroll
    for (int d4 = 0; d4 < 8; ++d4) {
      float4 v = *(const float4*)&Vsh[t][half * 32 + d4 * 4];
      acc4[d4].x += av * v.x;
      acc4[d4].y += av * v.y;
      acc4[d4].z += av * v.z;
      acc4[d4].w += av * v.w;
    }
  }
  _Float16* crow = ctx + (size_t)(g * 128 + p) * 1024 + h * 64 + half * 32;
#pragma unroll
  for (int i = 0; i < 4; ++i) {
    f16x8 hv;
    float4 lo = acc4[i * 2], hi = acc4[i * 2 + 1];
    hv[0] = (_Float16)lo.x; hv[1] = (_Float16)lo.y;
    hv[2] = (_Float16)lo.z; hv[3] = (_Float16)lo.w;
    hv[4] = (_Float16)hi.x; hv[5] = (_Float16)hi.y;
    hv[6] = (_Float16)hi.z; hv[7] = (_Float16)hi.w;
    *(f16x8*)&crow[i * 8] = hv;
  }
}

// ---------------- launch ----------------
extern "C" void kernel_launch(void* const* d_in, const int* in_sizes, int n_in,
                              void* d_out, int out_size, void* d_ws, size_t ws_size,
                              hipStream_t stream) {
  const float* V_token = (const float*)d_in[0];
  const float* L_token = (const float*)d_in[1];
  const float* Wq_w = (const float*)d_in[4];
  const float* Wq_b = (const float*)d_in[5];
  const float* Wk_w = (const float*)d_in[6];
  const float* Wk_b = (const float*)d_in[7];
  const float* Wv_w = (const float*)d_in[8];
  const float* Wv_b = (const float*)d_in[9];
  const float* Wo_w = (const float*)d_in[10];
  const float* Wo_b = (const float*)d_in[11];
  const float* Wm_w = (const float*)d_in[12];
  const float* Wm_b = (const float*)d_in[13];
  const float* Wv2_w = (const float*)d_in[14];
  const float* Wv2_b = (const float*)d_in[15];

  char* ws = (char*)d_ws;
  _Float16* hV = (_Float16*)ws;  ws += (size_t)4096 * 1024 * 2;
  _Float16* hL = (_Float16*)ws;  ws += (size_t)1024 * 1024 * 2;
  _Float16* hWq = (_Float16*)ws; ws += (size_t)1024 * 1024 * 2;
  _Float16* hWk = (_Float16*)ws; ws += (size_t)1024 * 1024 * 2;
  _Float16* hWv = (_Float16*)ws; ws += (size_t)1024 * 1024 * 2;
  _Float16* hWo = (_Float16*)ws; ws += (size_t)1024 * 1024 * 2;
  _Float16* hWm = (_Float16*)ws; ws += (size_t)1024 * 1024 * 2;
  _Float16* hWv2 = (_Float16*)ws; ws += (size_t)1024 * 1024 * 2;
  float* Qf = (float*)ws;        ws += (size_t)4096 * 1024 * 4;
  float* Kf = (float*)ws;        ws += (size_t)1024 * 1024 * 4;
  float* Vf = (float*)ws;        ws += (size_t)1024 * 1024 * 4;
  _Float16* ctx = (_Float16*)ws; ws += (size_t)4096 * 1024 * 2;
  _Float16* outh = (_Float16*)ws; ws += (size_t)4096 * 1024 * 2;

  float* mu = (float*)d_out;
  float* logv = mu + (size_t)4096 * 1024;
  float* attn = mu + (size_t)2 * 4096 * 1024;

  // zero the (mostly zero) attn output: 16*4096*1024 floats = 268 MB
  hipMemsetAsync(attn, 0, (size_t)16 * 4096 * 1024 * 4, stream);

  auto cvt = [&](const float* in, _Float16* out, size_t n) {
    int n4 = (int)(n / 4);
    int blocks = (n4 + 255) / 256;
    if (blocks > 2048) blocks = 2048;
    hipLaunchKernelGGL(cvt_f32_to_f16, dim3(blocks), dim3(256), 0, stream, in, out, n4);
  };
  cvt(V_token, hV, (size_t)4096 * 1024);
  cvt(L_token, hL, (size_t)1024 * 1024);
  cvt(Wq_w, hWq, (size_t)1024 * 1024);
  cvt(Wk_w, hWk, (size_t)1024 * 1024);
  cvt(Wv_w, hWv, (size_t)1024 * 1024);
  cvt(Wo_w, hWo, (size_t)1024 * 1024);
  cvt(Wm_w, hWm, (size_t)1024 * 1024);
  cvt(Wv2_w, hWv2, (size_t)1024 * 1024);

  // Q = V @ Wq^T + bq  (f32 out)
  hipLaunchKernelGGL((gemm_nt<false>), dim3(32, 8, 1), dim3(256), 0, stream,
                     hV, hWq, hWq, Wq_b, Wq_b, (void*)Qf, (void*)Qf);
  // K = L @ Wk^T + bk ; Vl = L @ Wv^T + bv  (fused via z)
  hipLaunchKernelGGL((gemm_nt<false>), dim3(8, 8, 2), dim3(256), 0, stream,
                     hL, hWk, hWv, Wk_b, Wv_b, (void*)Kf, (void*)Vf);
  // attention -> attn (d_out) + ctx (fp16)
  hipLaunchKernelGGL(attn_kernel, dim3(32, 16), dim3(256), 0, stream, Qf, Kf, Vf, attn, ctx);
  // out = ctx @ Wo^T + bo (fp16 out)
  hipLaunchKernelGGL((gemm_nt<true>), dim3(32, 8, 1), dim3(256), 0, stream,
                     ctx, hWo, hWo, Wo_b, Wo_b, (void*)outh, (void*)outh);
  // mu = out @ Wm^T + bm ; log_var = out @ Wv2^T + bv2  (fused via z)
  hipLaunchKernelGGL((gemm_nt<false>), dim3(32, 8, 2), dim3(256), 0, stream,
                     outh, hWm, hWv2, Wm_b, Wv2_b, (void*)mu, (void*)logv);
}

// Round 5
// 175.541 us; speedup vs baseline: 1.0073x; 1.0073x over previous
//
#include <hip/hip_runtime.h>
#include <hip/hip_fp16.h>

typedef _Float16 f16x8 __attribute__((ext_vector_type(8)));
typedef _Float16 f16x4 __attribute__((ext_vector_type(4)));
typedef float f32x4_t __attribute__((ext_vector_type(4)));

// ---------------- fused f32 -> f16 conversion (8 tensors, one launch) ----------------
struct CvtArgs {
  const float* src[8];
  _Float16* dst[8];
  int n4[8];
};

__global__ __launch_bounds__(256) void cvt_all(CvtArgs a) {
  const int t = blockIdx.y;
  const float4* __restrict__ in = (const float4*)a.src[t];
  f16x4* __restrict__ out = (f16x4*)a.dst[t];
  const int n4 = a.n4[t];
  const int stride = gridDim.x * blockDim.x;
  for (int i = blockIdx.x * blockDim.x + threadIdx.x; i < n4; i += stride) {
    float4 v = in[i];
    f16x4 h;
    h[0] = (_Float16)v.x; h[1] = (_Float16)v.y; h[2] = (_Float16)v.z; h[3] = (_Float16)v.w;
    out[i] = h;
  }
}

// ---------------- NT GEMM tile: C[128 rows, 64 cols] = A @ W^T + b ----------------
// BK=32, 4 waves (2 row x 2 col), per-wave 64x32 -> 4x2 fragments of 16x16x32 f16.
template <bool OUTH>
__device__ __forceinline__ void gemm_tile(const _Float16* __restrict__ A,
                                          const _Float16* __restrict__ W,
                                          const float* __restrict__ bias,
                                          void* __restrict__ Cv, int tm, int tn) {
  __shared__ _Float16 Ash[128][40];  // 32 + 8 pad: rows 16B aligned, banks spread
  __shared__ _Float16 Bsh[64][40];

  const int tid = threadIdx.x;
  const int lane = tid & 63;
  const int wave = tid >> 6;
  const int wr = wave >> 1;  // 0..1 (row 64-block)
  const int wc = wave & 1;   // 0..1 (col 32-block)

  const int ar = tid >> 1;          // 0..127
  const int ac = (tid & 1) * 16;    // 0,16
  const int br = tid >> 2;          // 0..63
  const int bc = (tid & 3) * 8;     // 0,8,16,24

  const _Float16* Ag = A + (size_t)(tm + ar) * 1024 + ac;
  const _Float16* Bg = W + (size_t)(tn + br) * 1024 + bc;

  f32x4_t acc[4][2];
#pragma unroll
  for (int m = 0; m < 4; ++m)
#pragma unroll
    for (int n = 0; n < 2; ++n) acc[m][n] = (f32x4_t){0.f, 0.f, 0.f, 0.f};

  uint4 pa0 = *(const uint4*)(Ag);
  uint4 pa1 = *(const uint4*)(Ag + 8);
  uint4 pb = *(const uint4*)(Bg);

  const int fr = lane & 15;
  const int kc = (lane >> 4) * 8;

#pragma unroll 1
  for (int kt = 0; kt < 32; ++kt) {
    __syncthreads();
    *(uint4*)&Ash[ar][ac] = pa0;
    *(uint4*)&Ash[ar][ac + 8] = pa1;
    *(uint4*)&Bsh[br][bc] = pb;
    __syncthreads();
    if (kt + 1 < 32) {
      const int ko = (kt + 1) * 32;
      pa0 = *(const uint4*)(Ag + ko);
      pa1 = *(const uint4*)(Ag + ko + 8);
      pb = *(const uint4*)(Bg + ko);
    }
    f16x8 af[4], bf[2];
#pragma unroll
    for (int m = 0; m < 4; ++m) af[m] = *(const f16x8*)&Ash[wr * 64 + m * 16 + fr][kc];
#pragma unroll
    for (int n = 0; n < 2; ++n) bf[n] = *(const f16x8*)&Bsh[wc * 32 + n * 16 + fr][kc];
#pragma unroll
    for (int m = 0; m < 4; ++m)
#pragma unroll
      for (int n = 0; n < 2; ++n)
        acc[m][n] = __builtin_amdgcn_mfma_f32_16x16x32_f16(af[m], bf[n], acc[m][n], 0, 0, 0);
  }

  // epilogue: C/D layout col=lane&15, row=(lane>>4)*4+reg
  const int cr = (lane >> 4) * 4;
  const int cc = lane & 15;
#pragma unroll
  for (int m = 0; m < 4; ++m) {
#pragma unroll
    for (int n = 0; n < 2; ++n) {
      const int col = tn + wc * 32 + n * 16 + cc;
      const float bv = bias[col];
#pragma unroll
      for (int r = 0; r < 4; ++r) {
        const int row = tm + wr * 64 + m * 16 + cr + r;
        float v = acc[m][n][r] + bv;
        if (OUTH)
          ((_Float16*)Cv)[(size_t)row * 1024 + col] = (_Float16)v;
        else
          ((float*)Cv)[(size_t)row * 1024 + col] = v;
      }
    }
  }
}

// ---------------- launch 2: fused QKV GEMMs + zero-fill of attn h<8 half ----------------
// grid (32,16,4). z=0: Q (M=4096). z=1: K (M=1024, bx<8). z=2: V (bx<8).
// z=3: full-row zero of attn[0:8,:,:] (134 MB) co-running with the GEMM blocks.
__global__ __launch_bounds__(256) void gemm_qkv_fill(
    const _Float16* __restrict__ hV, const _Float16* __restrict__ hL,
    const _Float16* __restrict__ hWq, const _Float16* __restrict__ hWk,
    const _Float16* __restrict__ hWv,
    const float* __restrict__ bq, const float* __restrict__ bk, const float* __restrict__ bv,
    float* __restrict__ Qf, float* __restrict__ Kf, float* __restrict__ Vf,
    float* __restrict__ attn) {
  const int z = blockIdx.z;
  if (z == 3) {
    // 512 blocks x 65536 floats = 8*4096*1024 floats (h<8 region), contiguous
    const int bl = blockIdx.y * 32 + blockIdx.x;
    float4* base = (float4*)attn + (size_t)bl * 16384;
    const float4 z4 = {0.f, 0.f, 0.f, 0.f};
#pragma unroll
    for (int c = threadIdx.x; c < 16384; c += 256) base[c] = z4;
    return;
  }
  if (z != 0 && blockIdx.x >= 8) return;  // K/V have M=1024 -> 8 row tiles

  const _Float16* A = (z == 0) ? hV : hL;
  const _Float16* W = (z == 0) ? hWq : (z == 1) ? hWk : hWv;
  const float* bias = (z == 0) ? bq : (z == 1) ? bk : bv;
  float* C = (z == 0) ? Qf : (z == 1) ? Kf : Vf;
  gemm_tile<false>(A, W, bias, (void*)C, blockIdx.x * 128, blockIdx.y * 64);
}

// ---------------- launch 4: Wo GEMM (f16 out) ----------------
__global__ __launch_bounds__(256) void gemm_wo(
    const _Float16* __restrict__ ctx, const _Float16* __restrict__ hWo,
    const float* __restrict__ bo, _Float16* __restrict__ outh) {
  gemm_tile<true>(ctx, hWo, bo, (void*)outh, blockIdx.x * 128, blockIdx.y * 64);
}

// ---------------- launch 5: mu/logvar GEMMs + skip-fill of attn h>=8 half ----------------
// grid (32,16,3). z=0: mu, z=1: log_var. z=2: zero rows of attn[8:16,:,:] EXCEPT the
// 32-col nonzero block already written by the attention kernel (which ran earlier).
__global__ __launch_bounds__(256) void gemm_mv_fill(
    const _Float16* __restrict__ outh,
    const _Float16* __restrict__ hWm, const _Float16* __restrict__ hWv2,
    const float* __restrict__ bm, const float* __restrict__ bv2,
    float* __restrict__ mu, float* __restrict__ logv, float* __restrict__ attn) {
  const int z = blockIdx.z;
  if (z == 2) {
    const int bl = blockIdx.y * 32 + blockIdx.x;  // 0..511, 64 rows each
    const int wave = threadIdx.x >> 6;
    const int lane = threadIdx.x & 63;
    const float4 z4 = {0.f, 0.f, 0.f, 0.f};
#pragma unroll
    for (int i = 0; i < 16; ++i) {
      const int rowIdx = bl * 64 + i * 4 + wave;  // 0..32767 over (h-8, p)
      const int p = rowIdx & 4095;
      const int g8 = (p >> 7) * 8;  // float4 index of the nonzero 32-col block
      float4* row = (float4*)(attn + ((size_t)(8 + (rowIdx >> 12)) * 4096 + p) * 1024);
#pragma unroll
      for (int c = lane; c < 256; c += 64) {
        if (c < g8 || c >= g8 + 8) row[c] = z4;
      }
    }
    return;
  }
  const _Float16* W = z ? hWv2 : hWm;
  const float* bias = z ? bv2 : bm;
  float* C = z ? logv : mu;
  gemm_tile<false>(outh, W, bias, (void*)C, blockIdx.x * 128, blockIdx.y * 64);
}

// ---------------- block-diagonal attention (unchanged; writes only nonzero blocks) ----
__global__ __launch_bounds__(256) void attn_kernel(
    const float* __restrict__ Q, const float* __restrict__ Kf, const float* __restrict__ Vf,
    float* __restrict__ attn_out,  // [16,4096,1024] slice of d_out
    _Float16* __restrict__ ctx) {  // [4096,1024] fp16
  const int g = blockIdx.x;
  const int h = blockIdx.y;

  __shared__ float Ksh[32][68];
  __shared__ float Vsh[32][68];
  __shared__ float Arow[128][33];

  const int tid = threadIdx.x;

#pragma unroll
  for (int i = 0; i < 8; ++i) {
    int idx = tid + i * 256;
    int t = idx >> 6, d = idx & 63;
    Ksh[t][d] = Kf[(size_t)(g * 32 + t) * 1024 + h * 64 + d];
    Vsh[t][d] = Vf[(size_t)(g * 32 + t) * 1024 + h * 64 + d];
  }
  __syncthreads();

  const int p = tid >> 1;
  const int half = tid & 1;

  float4 qv[16];
  const float* qrow = Q + (size_t)(g * 128 + p) * 1024 + h * 64;
#pragma unroll
  for (int i = 0; i < 16; ++i) qv[i] = ((const float4*)qrow)[i];

  float s[16];
#pragma unroll
  for (int j = 0; j < 16; ++j) {
    int t = half * 16 + j;
    float acc = 0.f;
#pragma unroll
    for (int d4 = 0; d4 < 16; ++d4) {
      float4 kv = *(const float4*)&Ksh[t][d4 * 4];
      acc += qv[d4].x * kv.x + qv[d4].y * kv.y + qv[d4].z * kv.z + qv[d4].w * kv.w;
    }
    s[j] = acc * 0.125f;
  }

  float m = s[0];
#pragma unroll
  for (int j = 1; j < 16; ++j) m = fmaxf(m, s[j]);
  m = fmaxf(m, __shfl_xor(m, 1));
  float e[16];
  float sum = 0.f;
#pragma unroll
  for (int j = 0; j < 16; ++j) {
    e[j] = __expf(s[j] - m);
    sum += e[j];
  }
  sum += __shfl_xor(sum, 1);
  const float inv = 1.0f / sum;

  float* arow_out =
      attn_out + (size_t)h * 4096 * 1024 + (size_t)(g * 128 + p) * 1024 + g * 32 + half * 16;
#pragma unroll
  for (int j = 0; j < 16; ++j) {
    float a = e[j] * inv;
    arow_out[j] = a;
    Arow[p][half * 16 + j] = a;
  }
  __syncthreads();

  float4 acc4[8];
#pragma unroll
  for (int i = 0; i < 8; ++i) acc4[i] = (float4){0.f, 0.f, 0.f, 0.f};
#pragma unroll
  for (int t = 0; t < 32; ++t) {
    float av = Arow[p][t];
#pragma unroll
    for (int d4 = 0; d4 < 8; ++d4) {
      float4 v = *(const float4*)&Vsh[t][half * 32 + d4 * 4];
      acc4[d4].x += av * v.x;
      acc4[d4].y += av * v.y;
      acc4[d4].z += av * v.z;
      acc4[d4].w += av * v.w;
    }
  }
  _Float16* crow = ctx + (size_t)(g * 128 + p) * 1024 + h * 64 + half * 32;
#pragma unroll
  for (int i = 0; i < 4; ++i) {
    f16x8 hv;
    float4 lo = acc4[i * 2], hi = acc4[i * 2 + 1];
    hv[0] = (_Float16)lo.x; hv[1] = (_Float16)lo.y;
    hv[2] = (_Float16)lo.z; hv[3] = (_Float16)lo.w;
    hv[4] = (_Float16)hi.x; hv[5] = (_Float16)hi.y;
    hv[6] = (_Float16)hi.z; hv[7] = (_Float16)hi.w;
    *(f16x8*)&crow[i * 8] = hv;
  }
}

// ---------------- launch ----------------
extern "C" void kernel_launch(void* const* d_in, const int* in_sizes, int n_in,
                              void* d_out, int out_size, void* d_ws, size_t ws_size,
                              hipStream_t stream) {
  const float* V_token = (const float*)d_in[0];
  const float* L_token = (const float*)d_in[1];
  const float* Wq_w = (const float*)d_in[4];
  const float* Wq_b = (const float*)d_in[5];
  const float* Wk_w = (const float*)d_in[6];
  const float* Wk_b = (const float*)d_in[7];
  const float* Wv_w = (const float*)d_in[8];
  const float* Wv_b = (const float*)d_in[9];
  const float* Wo_w = (const float*)d_in[10];
  const float* Wo_b = (const float*)d_in[11];
  const float* Wm_w = (const float*)d_in[12];
  const float* Wm_b = (const float*)d_in[13];
  const float* Wv2_w = (const float*)d_in[14];
  const float* Wv2_b = (const float*)d_in[15];

  char* ws = (char*)d_ws;
  _Float16* hV = (_Float16*)ws;   ws += (size_t)4096 * 1024 * 2;
  _Float16* hL = (_Float16*)ws;   ws += (size_t)1024 * 1024 * 2;
  _Float16* hWq = (_Float16*)ws;  ws += (size_t)1024 * 1024 * 2;
  _Float16* hWk = (_Float16*)ws;  ws += (size_t)1024 * 1024 * 2;
  _Float16* hWv = (_Float16*)ws;  ws += (size_t)1024 * 1024 * 2;
  _Float16* hWo = (_Float16*)ws;  ws += (size_t)1024 * 1024 * 2;
  _Float16* hWm = (_Float16*)ws;  ws += (size_t)1024 * 1024 * 2;
  _Float16* hWv2 = (_Float16*)ws; ws += (size_t)1024 * 1024 * 2;
  float* Qf = (float*)ws;         ws += (size_t)4096 * 1024 * 4;
  float* Kf = (float*)ws;         ws += (size_t)1024 * 1024 * 4;
  float* Vf = (float*)ws;         ws += (size_t)1024 * 1024 * 4;
  _Float16* ctx = (_Float16*)ws;  ws += (size_t)4096 * 1024 * 2;
  _Float16* outh = (_Float16*)ws; ws += (size_t)4096 * 1024 * 2;

  float* mu = (float*)d_out;
  float* logv = mu + (size_t)4096 * 1024;
  float* attn = mu + (size_t)2 * 4096 * 1024;

  // 1: all f32->f16 conversions in one launch
  CvtArgs ca;
  ca.src[0] = V_token; ca.dst[0] = hV;  ca.n4[0] = 4096 * 1024 / 4;
  ca.src[1] = L_token; ca.dst[1] = hL;  ca.n4[1] = 1024 * 1024 / 4;
  ca.src[2] = Wq_w;  ca.dst[2] = hWq;  ca.n4[2] = 1024 * 1024 / 4;
  ca.src[3] = Wk_w;  ca.dst[3] = hWk;  ca.n4[3] = 1024 * 1024 / 4;
  ca.src[4] = Wv_w;  ca.dst[4] = hWv;  ca.n4[4] = 1024 * 1024 / 4;
  ca.src[5] = Wo_w;  ca.dst[5] = hWo;  ca.n4[5] = 1024 * 1024 / 4;
  ca.src[6] = Wm_w;  ca.dst[6] = hWm;  ca.n4[6] = 1024 * 1024 / 4;
  ca.src[7] = Wv2_w; ca.dst[7] = hWv2; ca.n4[7] = 1024 * 1024 / 4;
  hipLaunchKernelGGL(cvt_all, dim3(128, 8), dim3(256), 0, stream, ca);

  // 2: Q,K,V GEMMs + zero-fill of attn[0:8] (co-running)
  hipLaunchKernelGGL(gemm_qkv_fill, dim3(32, 16, 4), dim3(256), 0, stream,
                     hV, hL, hWq, hWk, hWv, Wq_b, Wk_b, Wv_b, Qf, Kf, Vf, attn);

  // 3: attention -> attn nonzero blocks (d_out) + ctx (fp16)
  hipLaunchKernelGGL(attn_kernel, dim3(32, 16), dim3(256), 0, stream, Qf, Kf, Vf, attn, ctx);

  // 4: out = ctx @ Wo^T + bo (fp16 out)
  hipLaunchKernelGGL(gemm_wo, dim3(32, 16), dim3(256), 0, stream, ctx, hWo, Wo_b, outh);

  // 5: mu/log_var GEMMs + skip-fill of attn[8:16] (co-running, avoids nonzero blocks)
  hipLaunchKernelGGL(gemm_mv_fill, dim3(32, 16, 3), dim3(256), 0, stream,
                     outh, hWm, hWv2, Wm_b, Wv2_b, mu, logv, attn);
}